// Round 6
// baseline (39.320 us; speedup 1.0000x reference)
//
#include <hip/hip_runtime.h>

// WideModel: 8 hashed multi-hot features + sparse linear combine.
// Strategy R5: one WAVE per row. Dedupe via wave-private 128-slot LDS table
// with PLAIN stores ("write-winner" idiom, no atomics, no sort):
//   every pending lane stores packed=(bin<<6)|lane to tbl[h], reads back;
//   HW picks one deterministic winner per address. If slot holds our bin,
//   group resolved (keeper = exact lane match; duplicate lanes are in
//   lockstep so exactly one keeper per distinct bin). Else linear probe.
// Terminates: each round every written slot resolves >=1 whole bin-group.
// Overwritten (dead) entries are harmless: same-bin lanes always resolve in
// the same round, so a dead entry can never cause a double-keep.

constexpr int B = 16384;
constexpr int L = 50;
constexpr int SLOTS = 128;

struct KArgs {
    const int*   x[8];
    const float* w[8];
    const float* bias;
    float*       out;
};

__global__ __launch_bounds__(256) void wide_winner_kernel(KArgs a) {
    __shared__ unsigned tbl[4][SLOTS];            // 2 KB/block, wave-private

    const int wave = threadIdx.x >> 6;
    const int lane = threadIdx.x & 63;
    const int row  = (blockIdx.x << 2) | wave;

    // prefetch all 8 feature rows (each a coalesced 200 B segment)
    int v[8];
    #pragma unroll
    for (int f = 0; f < 8; ++f)
        v[f] = (lane < L) ? a.x[f][row * L + lane] : -1;

    // volatile: forbid store-to-load forwarding of the winner arbitration
    volatile unsigned* t = tbl[wave];

    float acc = 0.0f;

    #pragma unroll
    for (int f = 0; f < 8; ++f) {
        const bool valid = (v[f] >= 0);
        // compile-time magic-mul mod
        const unsigned bin = (f < 6) ? ((unsigned)v[f] % 100000u)
                                     : ((unsigned)v[f] % 1000000u);

        // clear table (packed < 2^26, so ~0 can never match a bin group)
        t[lane]      = 0xFFFFFFFFu;
        t[lane + 64] = 0xFFFFFFFFu;
        // same-wave LDS ops are processed in order; no barrier needed

        const unsigned packed = (bin << 6) | (unsigned)lane;
        unsigned h = (bin * 2654435761u) >> 25;   // top 7 bits -> [0,128)
        bool pend = valid, keep = false;

        while (__any(pend)) {
            if (pend) {
                t[h] = packed;                    // one deterministic winner
                const unsigned r = t[h];
                if ((r >> 6) == bin) {            // our bin owns the slot
                    keep = (r == packed);
                    pend = false;
                } else {
                    h = (h + 1) & (SLOTS - 1);    // foreign bin: probe on
                }
            }
        }

        if (keep) acc += a.w[f][bin];
    }

    // wave sum + single store (no atomics, no init kernel)
    #pragma unroll
    for (int off = 32; off; off >>= 1)
        acc += __shfl_xor(acc, off, 64);

    if (lane == 0) a.out[row] = acc + a.bias[0];
}

extern "C" void kernel_launch(void* const* d_in, const int* in_sizes, int n_in,
                              void* d_out, int out_size, void* d_ws, size_t ws_size,
                              hipStream_t stream) {
    KArgs a;
    for (int i = 0; i < 8; ++i) a.x[i] = (const int*)d_in[i];
    for (int i = 0; i < 8; ++i) a.w[i] = (const float*)d_in[8 + i];
    a.bias = (const float*)d_in[16];
    a.out  = (float*)d_out;

    wide_winner_kernel<<<B / 4, 256, 0, stream>>>(a);
}